// Round 10
// baseline (267.916 us; speedup 1.0000x reference)
//
#include <hip/hip_runtime.h>
#include <hip/hip_bf16.h>

#define SEQ 4096
#define EMB 1024
#define NHD 16
#define HDD 64

using bf16 = __hip_bfloat16;
using bf16x8 = __attribute__((ext_vector_type(8))) short;
using f32x4  = __attribute__((ext_vector_type(4))) float;
using f32x16 = __attribute__((ext_vector_type(16))) float;
using u32x4  = __attribute__((ext_vector_type(4))) unsigned int;
using u32x2  = __attribute__((ext_vector_type(2))) unsigned int;

#define MFMA16(a, b, c) __builtin_amdgcn_mfma_f32_16x16x32_bf16((a), (b), (c), 0, 0, 0)
#define MFMA32(a, b, c) __builtin_amdgcn_mfma_f32_32x32x16_bf16((a), (b), (c), 0, 0, 0)

// logit scale: 1/sqrt(64) * log2(e), folded into Q projection
#define QSCALE 0.1803368801111204f

__device__ __forceinline__ float b2f(bf16 b) { return __bfloat162float(b); }

__device__ __forceinline__ void gll16(const void* g, void* l) {
    __builtin_amdgcn_global_load_lds(
        (const __attribute__((address_space(1))) unsigned int*)g,
        (__attribute__((address_space(3))) unsigned int*)l, 16, 0, 0);
}

__device__ __forceinline__ unsigned pack_bf16x2(float a, float b) {
    __hip_bfloat162 p = __float22bfloat162_rn(make_float2(a, b));
    unsigned w;
    __builtin_memcpy(&w, &p, 4);
    return w;
}

// ---------------- prep: split f32 -> hi/lo bf16 ----------------
__global__ void split_kernel(const float* __restrict__ src, bf16* __restrict__ hi,
                             bf16* __restrict__ lo, int n4) {
    int i = blockIdx.x * blockDim.x + threadIdx.x;
    if (i >= n4) return;
    float4 v = ((const float4*)src)[i];
    float vv[4] = {v.x, v.y, v.z, v.w};
#pragma unroll
    for (int j = 0; j < 4; j++) {
        bf16 h = __float2bfloat16(vv[j]);
        hi[i * 4 + j] = h;
        lo[i * 4 + j] = __float2bfloat16(vv[j] - b2f(h));
    }
}

// ---------------- prep: W[k][n] f32 -> Wt[n][k] hi/lo bf16 (all 3 W) ------
__global__ void wtrans_kernel(const float* __restrict__ Wq, const float* __restrict__ Wk,
                              const float* __restrict__ Wv,
                              bf16* __restrict__ thq, bf16* __restrict__ tlq,
                              bf16* __restrict__ thk, bf16* __restrict__ tlk,
                              bf16* __restrict__ thv, bf16* __restrict__ tlv) {
    __shared__ float tile[32][33];
    const float* W;
    bf16 *wth, *wtl;
    if (blockIdx.z == 0) { W = Wq; wth = thq; wtl = tlq; }
    else if (blockIdx.z == 1) { W = Wk; wth = thk; wtl = tlk; }
    else { W = Wv; wth = thv; wtl = tlv; }
    int n0 = blockIdx.x * 32, k0 = blockIdx.y * 32;
    int tx = threadIdx.x, ty = threadIdx.y;
    for (int r = ty; r < 32; r += 8)
        tile[r][tx] = W[(k0 + r) * EMB + n0 + tx];
    __syncthreads();
    for (int r = ty; r < 32; r += 8) {
        float v = tile[tx][r];  // = W[k0+tx][n0+r]
        bf16 h = __float2bfloat16(v);
        wth[(n0 + r) * EMB + k0 + tx] = h;
        wtl[(n0 + r) * EMB + k0 + tx] = __float2bfloat16(v - b2f(h));
    }
}

// ---------------- fused QKV projection GEMM ----------------
template <int NTERMS>
__device__ __forceinline__ void proj_loop(
    const bf16* __restrict__ Ah, const bf16* __restrict__ Al,
    const bf16* __restrict__ Bth, const bf16* __restrict__ Btl,
    bf16* lAh, bf16* lAl, bf16* lBh, bf16* lBl,
    int m0, int n0, int t, f32x4 (&acc)[4][4]) {
    const int wid = t >> 6, lane = t & 63, lr = lane & 15, lg = lane >> 4;
    const int wr = (wid >> 1) * 64, wc = (wid & 1) * 64;
    for (int k0 = 0; k0 < EMB; k0 += 32) {
#pragma unroll
        for (int c = t; c < 512; c += 256) {
            int row = c >> 2, slot = c & 3;
            *(uint4*)&lAh[row * 40 + slot * 8] =
                *(const uint4*)&Ah[(m0 + row) * EMB + k0 + slot * 8];
            *(uint4*)&lBh[row * 40 + slot * 8] =
                *(const uint4*)&Bth[(n0 + row) * EMB + k0 + slot * 8];
            if constexpr (NTERMS == 3) {
                *(uint4*)&lAl[row * 40 + slot * 8] =
                    *(const uint4*)&Al[(m0 + row) * EMB + k0 + slot * 8];
                *(uint4*)&lBl[row * 40 + slot * 8] =
                    *(const uint4*)&Btl[(n0 + row) * EMB + k0 + slot * 8];
            }
        }
        __syncthreads();
        bf16x8 fah[4], fbh[4], fal[4], fbl[4];
#pragma unroll
        for (int i = 0; i < 4; i++) {
            fah[i] = *(const bf16x8*)&lAh[(wr + i * 16 + lr) * 40 + lg * 8];
            fbh[i] = *(const bf16x8*)&lBh[(wc + i * 16 + lr) * 40 + lg * 8];
            if constexpr (NTERMS == 3) {
                fal[i] = *(const bf16x8*)&lAl[(wr + i * 16 + lr) * 40 + lg * 8];
                fbl[i] = *(const bf16x8*)&lBl[(wc + i * 16 + lr) * 40 + lg * 8];
            }
        }
#pragma unroll
        for (int i = 0; i < 4; i++)
#pragma unroll
            for (int j = 0; j < 4; j++) {
                acc[i][j] = MFMA16(fah[i], fbh[j], acc[i][j]);
                if constexpr (NTERMS == 3) {
                    acc[i][j] = MFMA16(fah[i], fbl[j], acc[i][j]);
                    acc[i][j] = MFMA16(fal[i], fbh[j], acc[i][j]);
                }
            }
        __syncthreads();
    }
}

// grid (24, 32): x covers 3*EMB columns (8 tiles each for Q,K,V), y covers SEQ rows
__global__ __launch_bounds__(256) void proj_qkv(
    const bf16* __restrict__ xh, const bf16* __restrict__ xl,
    const bf16* __restrict__ thq, const bf16* __restrict__ tlq,
    const bf16* __restrict__ thk, const bf16* __restrict__ tlk,
    const bf16* __restrict__ thv,
    bf16* __restrict__ qh, bf16* __restrict__ ql,
    bf16* __restrict__ kh, bf16* __restrict__ kl, bf16* __restrict__ vt) {
    __shared__ __align__(16) bf16 lAh[128 * 40];
    __shared__ __align__(16) bf16 lAl[128 * 40];
    __shared__ __align__(16) bf16 lBh[128 * 40];
    __shared__ __align__(16) bf16 lBl[128 * 40];
    const int t = threadIdx.x;
    const int m0 = blockIdx.y * 128;
    const int which = blockIdx.x >> 3;
    const int n0 = (blockIdx.x & 7) * 128;

    f32x4 acc[4][4];
#pragma unroll
    for (int i = 0; i < 4; i++)
#pragma unroll
        for (int j = 0; j < 4; j++) acc[i][j] = (f32x4){0.f, 0.f, 0.f, 0.f};

    if (which == 0)
        proj_loop<3>(xh, xl, thq, tlq, lAh, lAl, lBh, lBl, m0, n0, t, acc);
    else if (which == 1)
        proj_loop<3>(xh, xl, thk, tlk, lAh, lAl, lBh, lBl, m0, n0, t, acc);
    else
        proj_loop<1>(xh, xl, thv, nullptr, lAh, lAl, lBh, lBl, m0, n0, t, acc);

    const int wid = t >> 6, lane = t & 63, lr = lane & 15, lg = lane >> 4;
    const int wr = (wid >> 1) * 64, wc = (wid & 1) * 64;

    if (which == 2) {
        // V: write directly transposed vt[(h*64+d)*SEQ + m], 8B packed stores
#pragma unroll
        for (int i = 0; i < 4; i++)
#pragma unroll
            for (int j = 0; j < 4; j++) {
                int n = n0 + wc + j * 16 + lr;       // column in V = h*64 + d
                int m = m0 + wr + i * 16 + lg * 4;   // 4 consecutive seq rows
                uint2 w;
                w.x = pack_bf16x2(acc[i][j][0], acc[i][j][1]);
                w.y = pack_bf16x2(acc[i][j][2], acc[i][j][3]);
                *(uint2*)&vt[(size_t)n * SEQ + m] = w;
            }
    } else {
        float scale = (which == 0) ? QSCALE : 1.0f;
        bf16* Chi = (which == 0) ? qh : kh;
        bf16* Clo = (which == 0) ? ql : kl;
#pragma unroll
        for (int i = 0; i < 4; i++)
#pragma unroll
            for (int j = 0; j < 4; j++)
#pragma unroll
                for (int q = 0; q < 4; q++) {
                    float cv = acc[i][j][q] * scale;
                    int m = m0 + wr + i * 16 + lg * 4 + q;
                    int n = n0 + wc + j * 16 + lr;
                    bf16 hv = __float2bfloat16(cv);
                    Chi[m * EMB + n] = hv;
                    Clo[m * EMB + n] = __float2bfloat16(cv - b2f(hv));
                }
    }
}

// ---------------- fused flash attention v7: split-K=2 ----------------
// Round-7 (v4) inner structure: 8 waves, QBLK=256, KVBLK=64, dbuf K/V (48KB),
// in-register P via cvt_pk+permlane32_swap, z16 MFMA-folded zero-init,
// balanced max/sum trees, defer-max. NEW: each block handles HALF the keys
// (32 tiles); grid 512 = 2 blocks/CU = 4 waves/SIMD (2x TLP). Partials
// (raw O, M, L in log2 domain) go to workspace; combine_kernel merges.
__global__ __launch_bounds__(512, 2) void attn_kernel(
    const bf16* __restrict__ qh, const bf16* __restrict__ ql,
    const bf16* __restrict__ kh, const bf16* __restrict__ kl,
    const bf16* __restrict__ vt, float* __restrict__ pO,
    float* __restrict__ pM, float* __restrict__ pL) {
    __shared__ __align__(16) bf16 lKV[2][3][64 * 64];  // 48 KB
    const int t = threadIdx.x;
    // XCD swizzle over 512 blocks (512 % 8 == 0): 64 consecutive swz per XCD
    // = 2 heads; within a head, same-half blocks are contiguous (K/V L2-fit).
    const int swz = (blockIdx.x & 7) * 64 + (blockIdx.x >> 3);
    const int h = swz >> 5;
    const int half = (swz >> 4) & 1;
    const int q0 = (swz & 15) * 256;
    const int pair = h * 16 + (swz & 15);
    const int wid = t >> 6, lane = t & 63;
    const int qq = lane & 31, hi = lane >> 5;
    const int qrow = q0 + wid * 32 + qq;

    // Q fragments (B-operand): col q = lane&31, k(d) = ds*16 + hi*8 + i
    bf16x8 fqh[4], fql[4];
    {
        const bf16* qbh = qh + (size_t)qrow * EMB + h * HDD + hi * 8;
        const bf16* qbl = ql + (size_t)qrow * EMB + h * HDD + hi * 8;
#pragma unroll
        for (int ds = 0; ds < 4; ds++) {
            fqh[ds] = *(const bf16x8*)(qbh + ds * 16);
            fql[ds] = *(const bf16x8*)(qbl + ds * 16);
        }
    }

    // staging: wave wid owns rows [wid*8, wid*8+8) of Kh/Kl/V (3 gll/lane/tile)
    const int srow = lane >> 3, slot = lane & 7;
    const int r = wid * 8 + srow;
    const int sb = (slot ^ (r & 7)) * 16;  // pre-swizzled global source
    const size_t KSTEP = (size_t)64 * EMB * 2, VSTEP = 64 * 2;
    const char* gp[3];
    gp[0] = (const char*)kh + ((size_t)r * EMB + h * HDD) * 2 + sb + half * 32 * KSTEP;
    gp[1] = (const char*)kl + ((size_t)r * EMB + h * HDD) * 2 + sb + half * 32 * KSTEP;
    gp[2] = (const char*)vt + ((size_t)(h * HDD + r) * SEQ) * 2 + sb + half * 32 * VSTEP;
    bf16* lp[3];
#pragma unroll
    for (int i = 0; i < 3; i++) lp[i] = &lKV[0][i][wid * 512];

    f32x16 z16;
#pragma unroll
    for (int rg = 0; rg < 16; rg++) z16[rg] = 0.f;
    f32x16 Ofr[2];
#pragma unroll
    for (int db = 0; db < 2; db++)
#pragma unroll
        for (int rg = 0; rg < 16; rg++) Ofr[db][rg] = 0.f;
    float Mr = -1e30f, Lr = 0.f;

    // prologue: stage tile 0 into buf 0
#pragma unroll
    for (int i = 0; i < 3; i++) {
        gll16(gp[i], lp[i]);
        gp[i] += (i < 2) ? KSTEP : VSTEP;
    }
    __syncthreads();

    for (int tk = 0; tk < 32; tk++) {
        const int cur = tk & 1;
        if (tk < 31) {
#pragma unroll
            for (int i = 0; i < 3; i++) {
                gll16(gp[i], lp[i] + (cur ^ 1) * 12288);
                gp[i] += (i < 2) ? KSTEP : VSTEP;
            }
        }
        const char* cKh = (const char*)&lKV[cur][0][0];
        const char* cKl = (const char*)&lKV[cur][1][0];
        const char* cV  = (const char*)&lKV[cur][2][0];

        // S^T = K Q^T, 3-term split, fp32 acc. A-frag row k = kb*32 + (lane&31)
        __builtin_amdgcn_s_setprio(1);
        f32x16 sfr[2];
#pragma unroll
        for (int kb = 0; kb < 2; kb++) {
            const int row = kb * 32 + qq;
            const char* rbh = cKh + row * 128;
            const char* rbl = cKl + row * 128;
            const int sw = (row & 7) << 4;
            f32x16 a;
#pragma unroll
            for (int ds = 0; ds < 4; ds++) {
                const int off = (ds * 32 + hi * 16) ^ sw;
                bf16x8 kbh_ = *(const bf16x8*)(rbh + off);
                bf16x8 kbl_ = *(const bf16x8*)(rbl + off);
                if (ds == 0)
                    a = MFMA32(kbh_, fqh[0], z16);  // fold zero-init into MFMA
                else
                    a = MFMA32(kbh_, fqh[ds], a);
                a = MFMA32(kbh_, fql[ds], a);
                a = MFMA32(kbl_, fqh[ds], a);
            }
            sfr[kb] = a;  // sfr[kb][reg]: k = kb*32 + (reg&3)+8*(reg>>2)+4*hi
        }
        __builtin_amdgcn_s_setprio(0);

        // online softmax (log2 domain); balanced max tree (depth 5)
        float m8[8];
#pragma unroll
        for (int i = 0; i < 8; i++)
            m8[i] = fmaxf(fmaxf(sfr[0][i], sfr[0][i + 8]),
                          fmaxf(sfr[1][i], sfr[1][i + 8]));
        float mx = fmaxf(fmaxf(fmaxf(m8[0], m8[1]), fmaxf(m8[2], m8[3])),
                         fmaxf(fmaxf(m8[4], m8[5]), fmaxf(m8[6], m8[7])));
        mx = fmaxf(mx, __shfl_xor(mx, 32));

        // defer-max: skip rescale while growth <= 11.5 (= ln-domain 8)
        bool resc = !__all(mx <= Mr + 11.5f);
        float mn = resc ? fmaxf(Mr, mx) : Mr;
#pragma unroll
        for (int kb = 0; kb < 2; kb++)
#pragma unroll
            for (int rg = 0; rg < 16; rg++)
                sfr[kb][rg] = __builtin_exp2f(sfr[kb][rg] - mn);
        // balanced sum tree (depth 5)
        float s16[16];
#pragma unroll
        for (int i = 0; i < 16; i++) s16[i] = sfr[0][i] + sfr[1][i];
        float s8[8];
#pragma unroll
        for (int i = 0; i < 8; i++) s8[i] = s16[i] + s16[i + 8];
        float ps = ((s8[0] + s8[1]) + (s8[2] + s8[3])) +
                   ((s8[4] + s8[5]) + (s8[6] + s8[7]));
        ps += __shfl_xor(ps, 32);
        if (resc) {
            float fac = __builtin_exp2f(Mr - mn);
            Mr = mn;
            Lr = Lr * fac + ps;
#pragma unroll
            for (int db = 0; db < 2; db++)
#pragma unroll
                for (int rg = 0; rg < 16; rg++) Ofr[db][rg] *= fac;
        } else {
            Lr += ps;
        }

        // pack P to bf16 + permlane32_swap -> PV B-frags, zero LDS traffic.
        bf16x8 pf[4];
#pragma unroll
        for (int sl = 0; sl < 4; sl++) {
            const int kb = sl >> 1, s8i = (sl & 1) * 8;
            unsigned w01 = pack_bf16x2(sfr[kb][s8i + 0], sfr[kb][s8i + 1]);
            unsigned w23 = pack_bf16x2(sfr[kb][s8i + 2], sfr[kb][s8i + 3]);
            unsigned w45 = pack_bf16x2(sfr[kb][s8i + 4], sfr[kb][s8i + 5]);
            unsigned w67 = pack_bf16x2(sfr[kb][s8i + 6], sfr[kb][s8i + 7]);
            u32x2 r0 = __builtin_amdgcn_permlane32_swap(w01, w45, false, false);
            u32x2 r1 = __builtin_amdgcn_permlane32_swap(w23, w67, false, false);
            u32x4 fw = {r0[0], r1[0], r0[1], r1[1]};
            bf16x8 pfv;
            __builtin_memcpy(&pfv, &fw, 16);
            pf[sl] = pfv;
        }

        // O^T += V^T P^T: A-frag row d = db*32 + (lane&31) from lV[d][k]
        __builtin_amdgcn_s_setprio(1);
#pragma unroll
        for (int sl = 0; sl < 4; sl++) {
#pragma unroll
            for (int db = 0; db < 2; db++) {
                const int vd = db * 32 + qq;
                const char* pv =
                    cV + vd * 128 + ((sl * 32 + hi * 16) ^ ((vd & 7) << 4));
                bf16x8 vf = *(const bf16x8*)pv;
                Ofr[db] = MFMA32(vf, pf[sl], Ofr[db]);
            }
        }
        __builtin_amdgcn_s_setprio(0);

        // one barrier per tile: drains prefetch (vmcnt0) + releases buf[cur]
        __syncthreads();
    }

    // epilogue: raw partials. pO[half][pair][qloc][d]; pM/pL[half][pair][qloc]
    const size_t qloc = wid * 32 + qq;
    float* pOb = pO + (((size_t)half * 256 + pair) * 256 + qloc) * 64;
#pragma unroll
    for (int db = 0; db < 2; db++)
#pragma unroll
        for (int rg = 0; rg < 4; rg++) {
            float4 o = make_float4(Ofr[db][rg * 4 + 0], Ofr[db][rg * 4 + 1],
                                   Ofr[db][rg * 4 + 2], Ofr[db][rg * 4 + 3]);
            *(float4*)(pOb + db * 32 + rg * 8 + hi * 4) = o;
        }
    if (hi == 0) {
        size_t mi = ((size_t)half * 256 + pair) * 256 + qloc;
        pM[mi] = Mr;
        pL[mi] = Lr;
    }
}

// ---------------- split-K combine ----------------
// out[q][h*64+d] = (O0*w0 + O1*w1) / (L0*w0 + L1*w1), w_i = exp2(M_i - max M)
__global__ __launch_bounds__(256) void combine_kernel(
    const float* __restrict__ pO, const float* __restrict__ pM,
    const float* __restrict__ pL, float* __restrict__ out) {
    const int t = blockIdx.x * 256 + threadIdx.x;  // 1M threads, one float4 each
    const int qrow = t >> 8;
    const int col = (t & 255) * 4;
    const int h = col >> 6, d = col & 63;
    const int qb = qrow >> 8, qloc = qrow & 255;
    const size_t i0 = (size_t)(h * 16 + qb) * 256 + qloc;
    const float M0 = pM[i0], M1 = pM[65536 + i0];
    const float L0 = pL[i0], L1 = pL[65536 + i0];
    const float Mf = fmaxf(M0, M1);
    const float w0 = __builtin_exp2f(M0 - Mf), w1 = __builtin_exp2f(M1 - Mf);
    const float inv = 1.0f / (L0 * w0 + L1 * w1);
    const float4 o0 = *(const float4*)(pO + i0 * 64 + d);
    const float4 o1 = *(const float4*)(pO + (size_t)4194304 + i0 * 64 + d);
    float4 o;
    o.x = (o0.x * w0 + o1.x * w1) * inv;
    o.y = (o0.y * w0 + o1.y * w1) * inv;
    o.z = (o0.z * w0 + o1.z * w1) * inv;
    o.w = (o0.w * w0 + o1.w * w1) * inv;
    *(float4*)(out + (size_t)qrow * EMB + col) = o;
}

// ---------------- launch ----------------
extern "C" void kernel_launch(void* const* d_in, const int* in_sizes, int n_in,
                              void* d_out, int out_size, void* d_ws, size_t ws_size,
                              hipStream_t stream) {
    const float* x = (const float*)d_in[0];
    const float* Wq = (const float*)d_in[1];
    const float* Wk = (const float*)d_in[2];
    const float* Wv = (const float*)d_in[3];
    float* out = (float*)d_out;

    char* ws = (char*)d_ws;
    size_t off = 0;
    auto alloc = [&](size_t elems) -> bf16* {
        bf16* p = (bf16*)(ws + off);
        off += elems * sizeof(bf16);
        return p;
    };
    // persistent through attn:
    bf16* qh = alloc((size_t)SEQ * EMB);
    bf16* ql = alloc((size_t)SEQ * EMB);
    bf16* kh = alloc((size_t)SEQ * EMB);
    bf16* kl = alloc((size_t)SEQ * EMB);
    bf16* vt = alloc((size_t)SEQ * EMB);
    // dead after proj_qkv (overlaid by split-K partials during attn):
    bf16* xh = alloc((size_t)SEQ * EMB);
    bf16* xl = alloc((size_t)SEQ * EMB);
    bf16* wthq = alloc((size_t)EMB * EMB);
    bf16* wtlq = alloc((size_t)EMB * EMB);
    bf16* wthk = alloc((size_t)EMB * EMB);
    bf16* wtlk = alloc((size_t)EMB * EMB);
    bf16* wthv = alloc((size_t)EMB * EMB);
    bf16* wtlv = alloc((size_t)EMB * EMB);
    // split-K partials overlay xh..wtlv (needs 34.6MB; region has 29.4MB +
    // 5.2MB beyond = within round-1-proven ws footprint of 79.8MB)
    float* pO = (float*)xh;                     // [2][256][256][64] f32, 33.5MB
    float* pM = pO + (size_t)2 * 256 * 256 * 64;  // [2][256][256] f32
    float* pL = pM + (size_t)2 * 256 * 256;
    (void)ws_size; (void)in_sizes; (void)n_in; (void)out_size;

    split_kernel<<<(SEQ * EMB / 4 + 255) / 256, 256, 0, stream>>>(x, xh, xl, SEQ * EMB / 4);
    wtrans_kernel<<<dim3(32, 32, 3), dim3(32, 8), 0, stream>>>(
        Wq, Wk, Wv, wthq, wtlq, wthk, wtlk, wthv, wtlv);
    proj_qkv<<<dim3(24, 32), 256, 0, stream>>>(
        xh, xl, wthq, wtlq, wthk, wtlk, wthv, qh, ql, kh, kl, vt);
    attn_kernel<<<512, 512, 0, stream>>>(qh, ql, kh, kl, vt, pO, pM, pL);
    combine_kernel<<<4096, 256, 0, stream>>>(pO, pM, pL, out);
}

// Round 11
// 255.593 us; speedup vs baseline: 1.0482x; 1.0482x over previous
//
#include <hip/hip_runtime.h>
#include <hip/hip_bf16.h>

#define SEQ 4096
#define EMB 1024
#define NHD 16
#define HDD 64

using bf16 = __hip_bfloat16;
using bf16x8 = __attribute__((ext_vector_type(8))) short;
using f32x4  = __attribute__((ext_vector_type(4))) float;
using f32x16 = __attribute__((ext_vector_type(16))) float;
using u32x4  = __attribute__((ext_vector_type(4))) unsigned int;
using u32x2  = __attribute__((ext_vector_type(2))) unsigned int;

#define MFMA16(a, b, c) __builtin_amdgcn_mfma_f32_16x16x32_bf16((a), (b), (c), 0, 0, 0)
#define MFMA32(a, b, c) __builtin_amdgcn_mfma_f32_32x32x16_bf16((a), (b), (c), 0, 0, 0)

// logit scale: 1/sqrt(64) * log2(e), folded into Q projection
#define QSCALE 0.1803368801111204f

__device__ __forceinline__ float b2f(bf16 b) { return __bfloat162float(b); }

__device__ __forceinline__ void gll16(const void* g, void* l) {
    __builtin_amdgcn_global_load_lds(
        (const __attribute__((address_space(1))) unsigned int*)g,
        (__attribute__((address_space(3))) unsigned int*)l, 16, 0, 0);
}

__device__ __forceinline__ unsigned pack_bf16x2(float a, float b) {
    __hip_bfloat162 p = __float22bfloat162_rn(make_float2(a, b));
    unsigned w;
    __builtin_memcpy(&w, &p, 4);
    return w;
}

// ---------------- prep: split f32 -> hi/lo bf16 ----------------
__global__ void split_kernel(const float* __restrict__ src, bf16* __restrict__ hi,
                             bf16* __restrict__ lo, int n4) {
    int i = blockIdx.x * blockDim.x + threadIdx.x;
    if (i >= n4) return;
    float4 v = ((const float4*)src)[i];
    float vv[4] = {v.x, v.y, v.z, v.w};
#pragma unroll
    for (int j = 0; j < 4; j++) {
        bf16 h = __float2bfloat16(vv[j]);
        hi[i * 4 + j] = h;
        lo[i * 4 + j] = __float2bfloat16(vv[j] - b2f(h));
    }
}

// ---------------- prep: W[k][n] f32 -> Wt[n][k] hi/lo bf16 (all 3 W) ------
__global__ void wtrans_kernel(const float* __restrict__ Wq, const float* __restrict__ Wk,
                              const float* __restrict__ Wv,
                              bf16* __restrict__ thq, bf16* __restrict__ tlq,
                              bf16* __restrict__ thk, bf16* __restrict__ tlk,
                              bf16* __restrict__ thv, bf16* __restrict__ tlv) {
    __shared__ float tile[32][33];
    const float* W;
    bf16 *wth, *wtl;
    if (blockIdx.z == 0) { W = Wq; wth = thq; wtl = tlq; }
    else if (blockIdx.z == 1) { W = Wk; wth = thk; wtl = tlk; }
    else { W = Wv; wth = thv; wtl = tlv; }
    int n0 = blockIdx.x * 32, k0 = blockIdx.y * 32;
    int tx = threadIdx.x, ty = threadIdx.y;
    for (int r = ty; r < 32; r += 8)
        tile[r][tx] = W[(k0 + r) * EMB + n0 + tx];
    __syncthreads();
    for (int r = ty; r < 32; r += 8) {
        float v = tile[tx][r];  // = W[k0+tx][n0+r]
        bf16 h = __float2bfloat16(v);
        wth[(n0 + r) * EMB + k0 + tx] = h;
        wtl[(n0 + r) * EMB + k0 + tx] = __float2bfloat16(v - b2f(h));
    }
}

// ---------------- fused QKV projection GEMM ----------------
template <int NTERMS>
__device__ __forceinline__ void proj_loop(
    const bf16* __restrict__ Ah, const bf16* __restrict__ Al,
    const bf16* __restrict__ Bth, const bf16* __restrict__ Btl,
    bf16* lAh, bf16* lAl, bf16* lBh, bf16* lBl,
    int m0, int n0, int t, f32x4 (&acc)[4][4]) {
    const int wid = t >> 6, lane = t & 63, lr = lane & 15, lg = lane >> 4;
    const int wr = (wid >> 1) * 64, wc = (wid & 1) * 64;
    for (int k0 = 0; k0 < EMB; k0 += 32) {
#pragma unroll
        for (int c = t; c < 512; c += 256) {
            int row = c >> 2, slot = c & 3;
            *(uint4*)&lAh[row * 40 + slot * 8] =
                *(const uint4*)&Ah[(m0 + row) * EMB + k0 + slot * 8];
            *(uint4*)&lBh[row * 40 + slot * 8] =
                *(const uint4*)&Bth[(n0 + row) * EMB + k0 + slot * 8];
            if constexpr (NTERMS == 3) {
                *(uint4*)&lAl[row * 40 + slot * 8] =
                    *(const uint4*)&Al[(m0 + row) * EMB + k0 + slot * 8];
                *(uint4*)&lBl[row * 40 + slot * 8] =
                    *(const uint4*)&Btl[(n0 + row) * EMB + k0 + slot * 8];
            }
        }
        __syncthreads();
        bf16x8 fah[4], fbh[4], fal[4], fbl[4];
#pragma unroll
        for (int i = 0; i < 4; i++) {
            fah[i] = *(const bf16x8*)&lAh[(wr + i * 16 + lr) * 40 + lg * 8];
            fbh[i] = *(const bf16x8*)&lBh[(wc + i * 16 + lr) * 40 + lg * 8];
            if constexpr (NTERMS == 3) {
                fal[i] = *(const bf16x8*)&lAl[(wr + i * 16 + lr) * 40 + lg * 8];
                fbl[i] = *(const bf16x8*)&lBl[(wc + i * 16 + lr) * 40 + lg * 8];
            }
        }
#pragma unroll
        for (int i = 0; i < 4; i++)
#pragma unroll
            for (int j = 0; j < 4; j++) {
                acc[i][j] = MFMA16(fah[i], fbh[j], acc[i][j]);
                if constexpr (NTERMS == 3) {
                    acc[i][j] = MFMA16(fah[i], fbl[j], acc[i][j]);
                    acc[i][j] = MFMA16(fal[i], fbh[j], acc[i][j]);
                }
            }
        __syncthreads();
    }
}

// grid (24, 32): x covers 3*EMB columns (8 tiles each for Q,K,V), y covers SEQ rows
__global__ __launch_bounds__(256) void proj_qkv(
    const bf16* __restrict__ xh, const bf16* __restrict__ xl,
    const bf16* __restrict__ thq, const bf16* __restrict__ tlq,
    const bf16* __restrict__ thk, const bf16* __restrict__ tlk,
    const bf16* __restrict__ thv,
    bf16* __restrict__ qh, bf16* __restrict__ ql,
    bf16* __restrict__ kh, bf16* __restrict__ kl, bf16* __restrict__ vt) {
    __shared__ __align__(16) bf16 lAh[128 * 40];
    __shared__ __align__(16) bf16 lAl[128 * 40];
    __shared__ __align__(16) bf16 lBh[128 * 40];
    __shared__ __align__(16) bf16 lBl[128 * 40];
    const int t = threadIdx.x;
    const int m0 = blockIdx.y * 128;
    const int which = blockIdx.x >> 3;
    const int n0 = (blockIdx.x & 7) * 128;

    f32x4 acc[4][4];
#pragma unroll
    for (int i = 0; i < 4; i++)
#pragma unroll
        for (int j = 0; j < 4; j++) acc[i][j] = (f32x4){0.f, 0.f, 0.f, 0.f};

    if (which == 0)
        proj_loop<3>(xh, xl, thq, tlq, lAh, lAl, lBh, lBl, m0, n0, t, acc);
    else if (which == 1)
        proj_loop<3>(xh, xl, thk, tlk, lAh, lAl, lBh, lBl, m0, n0, t, acc);
    else
        proj_loop<1>(xh, xl, thv, nullptr, lAh, lAl, lBh, lBl, m0, n0, t, acc);

    const int wid = t >> 6, lane = t & 63, lr = lane & 15, lg = lane >> 4;
    const int wr = (wid >> 1) * 64, wc = (wid & 1) * 64;

    if (which == 2) {
        // V: write directly transposed vt[(h*64+d)*SEQ + m], 8B packed stores
#pragma unroll
        for (int i = 0; i < 4; i++)
#pragma unroll
            for (int j = 0; j < 4; j++) {
                int n = n0 + wc + j * 16 + lr;       // column in V = h*64 + d
                int m = m0 + wr + i * 16 + lg * 4;   // 4 consecutive seq rows
                uint2 w;
                w.x = pack_bf16x2(acc[i][j][0], acc[i][j][1]);
                w.y = pack_bf16x2(acc[i][j][2], acc[i][j][3]);
                *(uint2*)&vt[(size_t)n * SEQ + m] = w;
            }
    } else {
        float scale = (which == 0) ? QSCALE : 1.0f;
        bf16* Chi = (which == 0) ? qh : kh;
        bf16* Clo = (which == 0) ? ql : kl;
#pragma unroll
        for (int i = 0; i < 4; i++)
#pragma unroll
            for (int j = 0; j < 4; j++)
#pragma unroll
                for (int q = 0; q < 4; q++) {
                    float cv = acc[i][j][q] * scale;
                    int m = m0 + wr + i * 16 + lg * 4 + q;
                    int n = n0 + wc + j * 16 + lr;
                    bf16 hv = __float2bfloat16(cv);
                    Chi[m * EMB + n] = hv;
                    Clo[m * EMB + n] = __float2bfloat16(cv - b2f(hv));
                }
    }
}

// ---------------- fused flash attention v8: split-K=2, low-reg ----------
// v7 structure, but kb-SEQUENTIAL inner loop: only ONE f32x16 score reg live
// (16 vs 32), pf 8 vs 16, no persistent z16. __launch_bounds__(512,4) pins
// total regs <=128/wave so TWO 8-wave blocks co-reside per CU (4 waves/SIMD).
__global__ __launch_bounds__(512, 4) void attn_kernel(
    const bf16* __restrict__ qh, const bf16* __restrict__ ql,
    const bf16* __restrict__ kh, const bf16* __restrict__ kl,
    const bf16* __restrict__ vt, float* __restrict__ pO,
    float* __restrict__ pM, float* __restrict__ pL) {
    __shared__ __align__(16) bf16 lKV[2][3][64 * 64];  // 48 KB
    const int t = threadIdx.x;
    // XCD swizzle over 512 blocks: 64 consecutive swz per XCD = 2 heads
    const int swz = (blockIdx.x & 7) * 64 + (blockIdx.x >> 3);
    const int h = swz >> 5;
    const int half = (swz >> 4) & 1;
    const int q0 = (swz & 15) * 256;
    const int pair = h * 16 + (swz & 15);
    const int wid = t >> 6, lane = t & 63;
    const int qq = lane & 31, hi = lane >> 5;
    const int qrow = q0 + wid * 32 + qq;

    // Q fragments (B-operand): col q = lane&31, k(d) = ds*16 + hi*8 + i
    bf16x8 fqh[4], fql[4];
    {
        const bf16* qbh = qh + (size_t)qrow * EMB + h * HDD + hi * 8;
        const bf16* qbl = ql + (size_t)qrow * EMB + h * HDD + hi * 8;
#pragma unroll
        for (int ds = 0; ds < 4; ds++) {
            fqh[ds] = *(const bf16x8*)(qbh + ds * 16);
            fql[ds] = *(const bf16x8*)(qbl + ds * 16);
        }
    }

    // staging: wave wid owns rows [wid*8, wid*8+8) of Kh/Kl/V (3 gll/lane/tile)
    const int srow = lane >> 3, slot = lane & 7;
    const int r = wid * 8 + srow;
    const int sb = (slot ^ (r & 7)) * 16;  // pre-swizzled global source
    const size_t KSTEP = (size_t)64 * EMB * 2, VSTEP = 64 * 2;
    const char* gp[3];
    gp[0] = (const char*)kh + ((size_t)r * EMB + h * HDD) * 2 + sb + half * 32 * KSTEP;
    gp[1] = (const char*)kl + ((size_t)r * EMB + h * HDD) * 2 + sb + half * 32 * KSTEP;
    gp[2] = (const char*)vt + ((size_t)(h * HDD + r) * SEQ) * 2 + sb + half * 32 * VSTEP;
    bf16* lp[3];
#pragma unroll
    for (int i = 0; i < 3; i++) lp[i] = &lKV[0][i][wid * 512];

    f32x16 Ofr[2];
#pragma unroll
    for (int db = 0; db < 2; db++)
#pragma unroll
        for (int rg = 0; rg < 16; rg++) Ofr[db][rg] = 0.f;
    float Mr = -1e30f, Lr = 0.f;

    // prologue: stage tile 0 into buf 0
#pragma unroll
    for (int i = 0; i < 3; i++) {
        gll16(gp[i], lp[i]);
        gp[i] += (i < 2) ? KSTEP : VSTEP;
    }
    __syncthreads();

    for (int tk = 0; tk < 32; tk++) {
        const int cur = tk & 1;
        if (tk < 31) {
#pragma unroll
            for (int i = 0; i < 3; i++) {
                gll16(gp[i], lp[i] + (cur ^ 1) * 12288);
                gp[i] += (i < 2) ? KSTEP : VSTEP;
            }
        }
        const char* cKh = (const char*)&lKV[cur][0][0];
        const char* cKl = (const char*)&lKV[cur][1][0];
        const char* cV  = (const char*)&lKV[cur][2][0];

        // kb-sequential: QK^T + softmax + pack + PV per 32-key sub-tile
#pragma unroll
        for (int kb = 0; kb < 2; kb++) {
            const int row = kb * 32 + qq;
            const char* rbh = cKh + row * 128;
            const char* rbl = cKl + row * 128;
            const int sw = (row & 7) << 4;
            f32x16 a;
#pragma unroll
            for (int rg = 0; rg < 16; rg++) a[rg] = 0.f;
            __builtin_amdgcn_s_setprio(1);
#pragma unroll
            for (int ds = 0; ds < 4; ds++) {
                const int off = (ds * 32 + hi * 16) ^ sw;
                bf16x8 kbh_ = *(const bf16x8*)(rbh + off);
                bf16x8 kbl_ = *(const bf16x8*)(rbl + off);
                a = MFMA32(kbh_, fqh[ds], a);
                a = MFMA32(kbh_, fql[ds], a);
                a = MFMA32(kbl_, fqh[ds], a);
            }
            __builtin_amdgcn_s_setprio(0);
            // a[rg]: S2[q=qq][k = kb*32 + (rg&3)+8*(rg>>2)+4*hi]

            // softmax sub-update (log2 domain); balanced max tree (depth 4)
            float m4[4];
#pragma unroll
            for (int i = 0; i < 4; i++)
                m4[i] = fmaxf(fmaxf(a[i], a[i + 4]), fmaxf(a[i + 8], a[i + 12]));
            float mx = fmaxf(fmaxf(m4[0], m4[1]), fmaxf(m4[2], m4[3]));
            mx = fmaxf(mx, __shfl_xor(mx, 32));

            // defer-max: skip rescale while growth <= 11.5 (= ln-domain 8)
            bool resc = !__all(mx <= Mr + 11.5f);
            float mn = resc ? fmaxf(Mr, mx) : Mr;
#pragma unroll
            for (int rg = 0; rg < 16; rg++)
                a[rg] = __builtin_exp2f(a[rg] - mn);
            // balanced sum tree
            float s4[4];
#pragma unroll
            for (int i = 0; i < 4; i++)
                s4[i] = (a[i] + a[i + 4]) + (a[i + 8] + a[i + 12]);
            float ps = (s4[0] + s4[1]) + (s4[2] + s4[3]);
            ps += __shfl_xor(ps, 32);
            if (resc) {
                float fac = __builtin_exp2f(Mr - mn);
                Mr = mn;
                Lr = Lr * fac + ps;
#pragma unroll
                for (int db = 0; db < 2; db++)
#pragma unroll
                    for (int rg = 0; rg < 16; rg++) Ofr[db][rg] *= fac;
            } else {
                Lr += ps;
            }

            // pack P (32 keys) -> 2 PV B-frags via cvt_pk + permlane32_swap
            bf16x8 pf[2];
#pragma unroll
            for (int sl = 0; sl < 2; sl++) {
                const int s8i = sl * 8;
                unsigned w01 = pack_bf16x2(a[s8i + 0], a[s8i + 1]);
                unsigned w23 = pack_bf16x2(a[s8i + 2], a[s8i + 3]);
                unsigned w45 = pack_bf16x2(a[s8i + 4], a[s8i + 5]);
                unsigned w67 = pack_bf16x2(a[s8i + 6], a[s8i + 7]);
                u32x2 r0 = __builtin_amdgcn_permlane32_swap(w01, w45, false, false);
                u32x2 r1 = __builtin_amdgcn_permlane32_swap(w23, w67, false, false);
                u32x4 fw = {r0[0], r1[0], r0[1], r1[1]};
                bf16x8 pfv;
                __builtin_memcpy(&pfv, &fw, 16);
                pf[sl] = pfv;
            }

            // O^T += V^T P^T for this sub-tile (global slice = kb*2 + sl)
            __builtin_amdgcn_s_setprio(1);
#pragma unroll
            for (int sl = 0; sl < 2; sl++) {
#pragma unroll
                for (int db = 0; db < 2; db++) {
                    const int vd = db * 32 + qq;
                    const char* pv = cV + vd * 128 +
                        (((kb * 2 + sl) * 32 + hi * 16) ^ ((vd & 7) << 4));
                    bf16x8 vf = *(const bf16x8*)pv;
                    Ofr[db] = MFMA32(vf, pf[sl], Ofr[db]);
                }
            }
            __builtin_amdgcn_s_setprio(0);
        }

        // one barrier per tile: drains prefetch (vmcnt0) + releases buf[cur]
        __syncthreads();
    }

    // epilogue: raw partials. pO[half][pair][qloc][d]; pM/pL[half][pair][qloc]
    const size_t qloc = wid * 32 + qq;
    float* pOb = pO + (((size_t)half * 256 + pair) * 256 + qloc) * 64;
#pragma unroll
    for (int db = 0; db < 2; db++)
#pragma unroll
        for (int rg = 0; rg < 4; rg++) {
            float4 o = make_float4(Ofr[db][rg * 4 + 0], Ofr[db][rg * 4 + 1],
                                   Ofr[db][rg * 4 + 2], Ofr[db][rg * 4 + 3]);
            *(float4*)(pOb + db * 32 + rg * 8 + hi * 4) = o;
        }
    if (hi == 0) {
        size_t mi = ((size_t)half * 256 + pair) * 256 + qloc;
        pM[mi] = Mr;
        pL[mi] = Lr;
    }
}

// ---------------- split-K combine ----------------
// out[q][h*64+d] = (O0*w0 + O1*w1) / (L0*w0 + L1*w1), w_i = exp2(M_i - max M)
__global__ __launch_bounds__(256) void combine_kernel(
    const float* __restrict__ pO, const float* __restrict__ pM,
    const float* __restrict__ pL, float* __restrict__ out) {
    const int t = blockIdx.x * 256 + threadIdx.x;  // 1M threads, one float4 each
    const int qrow = t >> 8;
    const int col = (t & 255) * 4;
    const int h = col >> 6, d = col & 63;
    const int qb = qrow >> 8, qloc = qrow & 255;
    const size_t i0 = (size_t)(h * 16 + qb) * 256 + qloc;
    const float M0 = pM[i0], M1 = pM[65536 + i0];
    const float L0 = pL[i0], L1 = pL[65536 + i0];
    const float Mf = fmaxf(M0, M1);
    const float w0 = __builtin_exp2f(M0 - Mf), w1 = __builtin_exp2f(M1 - Mf);
    const float inv = 1.0f / (L0 * w0 + L1 * w1);
    const float4 o0 = *(const float4*)(pO + i0 * 64 + d);
    const float4 o1 = *(const float4*)(pO + (size_t)4194304 + i0 * 64 + d);
    float4 o;
    o.x = (o0.x * w0 + o1.x * w1) * inv;
    o.y = (o0.y * w0 + o1.y * w1) * inv;
    o.z = (o0.z * w0 + o1.z * w1) * inv;
    o.w = (o0.w * w0 + o1.w * w1) * inv;
    *(float4*)(out + (size_t)qrow * EMB + col) = o;
}

// ---------------- launch ----------------
extern "C" void kernel_launch(void* const* d_in, const int* in_sizes, int n_in,
                              void* d_out, int out_size, void* d_ws, size_t ws_size,
                              hipStream_t stream) {
    const float* x = (const float*)d_in[0];
    const float* Wq = (const float*)d_in[1];
    const float* Wk = (const float*)d_in[2];
    const float* Wv = (const float*)d_in[3];
    float* out = (float*)d_out;

    char* ws = (char*)d_ws;
    size_t off = 0;
    auto alloc = [&](size_t elems) -> bf16* {
        bf16* p = (bf16*)(ws + off);
        off += elems * sizeof(bf16);
        return p;
    };
    // persistent through attn:
    bf16* qh = alloc((size_t)SEQ * EMB);
    bf16* ql = alloc((size_t)SEQ * EMB);
    bf16* kh = alloc((size_t)SEQ * EMB);
    bf16* kl = alloc((size_t)SEQ * EMB);
    bf16* vt = alloc((size_t)SEQ * EMB);
    // dead after proj_qkv (overlaid by split-K partials during attn):
    bf16* xh = alloc((size_t)SEQ * EMB);
    bf16* xl = alloc((size_t)SEQ * EMB);
    bf16* wthq = alloc((size_t)EMB * EMB);
    bf16* wtlq = alloc((size_t)EMB * EMB);
    bf16* wthk = alloc((size_t)EMB * EMB);
    bf16* wtlk = alloc((size_t)EMB * EMB);
    bf16* wthv = alloc((size_t)EMB * EMB);
    bf16* wtlv = alloc((size_t)EMB * EMB);
    // split-K partials overlay xh..wtlv
    float* pO = (float*)xh;                       // [2][256][256][64] f32
    float* pM = pO + (size_t)2 * 256 * 256 * 64;  // [2][256][256] f32
    float* pL = pM + (size_t)2 * 256 * 256;
    (void)ws_size; (void)in_sizes; (void)n_in; (void)out_size;

    split_kernel<<<(SEQ * EMB / 4 + 255) / 256, 256, 0, stream>>>(x, xh, xl, SEQ * EMB / 4);
    wtrans_kernel<<<dim3(32, 32, 3), dim3(32, 8), 0, stream>>>(
        Wq, Wk, Wv, wthq, wtlq, wthk, wtlk, wthv, wtlv);
    proj_qkv<<<dim3(24, 32), 256, 0, stream>>>(
        xh, xl, wthq, wtlq, wthk, wtlk, wthv, qh, ql, kh, kl, vt);
    attn_kernel<<<512, 512, 0, stream>>>(qh, ql, kh, kl, vt, pO, pM, pL);
    combine_kernel<<<4096, 256, 0, stream>>>(pO, pM, pL, out);
}